// Round 5
// baseline (3721.208 us; speedup 1.0000x reference)
//
#include <hip/hip_runtime.h>
#include <hip/hip_bf16.h>
#include <cstddef>
#include <cstdint>

// Problem constants
#define NB 32          // batch
#define NS 512         // seq len
#define ND 512         // d_model == hid
#define NG 2048        // 4*hid gate cols per layer

// ws layout. Poison-mailbox + writer-wave + RUNTIME XCD-LOCAL fast path.
//  claim region (4KB): [0] cntL0 [1] cntL1 [2] total [3] modeL0 [4] modeL1
//                      [32..95] flags (bp, small-ws fallback) [128..255] xcdtab
//  h1  : 16 x 32KB  layer-1 recurrence slots (slot = t&15, poison recycle)
//  h0f : 16 x 32KB  layer-0 FAST recurrence slots (slot = t&15, poison recycle)
//  h0m : 512 x 32KB write-once mirror of h0 (FULL) or 32 x 32KB + bp (SMALL)
// One 32KB slot, element (b,k):
//   (b>>4)*16384 + (k>>5)*1024 + ((k>>3)&3)*256 + (b&15)*16 + (k&7)*2
// Roles are CLAIMED at runtime by physical XCD (s_getreg HW_REG_XCC_ID,
// HW-verified m09): L0 slices by XCD0 blocks, L1 by XCD1; shortfalls filled
// by any block after a timeout (sets the layer's mixed flag). fastL is true
// only if the layer's mode flag is clean AND all 64 claimed producers report
// the same XCD -> producers+consumers share one L2 -> sc0-only stores/polls
// are exactly coherent (same L2; sc0 bypasses the per-CU L1). Cross-layer
// h0->L1 always uses relaxed agent-scope atomics on the mirror (R4-proven).
// Non-fast layers use the agent path everywhere (== R4 semantics).
// Legit |h|<1 never encodes bf16 0xFFFF -> 0xFFFFFFFF is impossible; publish
// and check granularity are both 4B -> no torn reads.
#define CLAIM_BYTES 4096
#define H1_OFF   CLAIM_BYTES
#define H0F_OFF  (H1_OFF + 16 * 32768)
#define H0M_OFF  (H0F_OFF + 16 * 32768)          // 1,052,672
#define WS_FULL  ((size_t)H0M_OFF + 512ull * 32768ull)   // 17.8 MB
#define WS_SMALL ((size_t)H0M_OFF + 32ull * 32768ull)    // 2.1 MB

#define POISON   0xFFFFFFFFu
#define SPIN_LIM (1 << 17)

typedef __attribute__((ext_vector_type(8))) short short8;
typedef __attribute__((ext_vector_type(8))) __bf16 bf16x8;
typedef __attribute__((ext_vector_type(4))) float f32x4;
typedef __attribute__((ext_vector_type(4))) unsigned int u32x4;

static __device__ __forceinline__ unsigned short f2bf(float f) {
  __hip_bfloat16 h = __float2bfloat16(f);
  return __builtin_bit_cast(unsigned short, h);
}

static __device__ __forceinline__ short8 pack8(float4 a, float4 b) {
  short8 r;
  r[0] = (short)f2bf(a.x); r[1] = (short)f2bf(a.y);
  r[2] = (short)f2bf(a.z); r[3] = (short)f2bf(a.w);
  r[4] = (short)f2bf(b.x); r[5] = (short)f2bf(b.y);
  r[6] = (short)f2bf(b.z); r[7] = (short)f2bf(b.w);
  return r;
}

static __device__ __forceinline__ unsigned long long aload64(const unsigned char* p) {
  return __hip_atomic_load(reinterpret_cast<const unsigned long long*>(p),
                           __ATOMIC_RELAXED, __HIP_MEMORY_SCOPE_AGENT);
}
static __device__ __forceinline__ int aload_i(const int* p) {
  return __hip_atomic_load(p, __ATOMIC_RELAXED, __HIP_MEMORY_SCOPE_AGENT);
}
static __device__ __forceinline__ int aload_acq(const int* p) {
  return __hip_atomic_load(p, __ATOMIC_ACQUIRE, __HIP_MEMORY_SCOPE_AGENT);
}
static __device__ __forceinline__ void astore_i(int* p, int v) {
  __hip_atomic_store(p, v, __ATOMIC_RELAXED, __HIP_MEMORY_SCOPE_AGENT);
}
static __device__ __forceinline__ void astore_u(unsigned char* p, unsigned v) {
  __hip_atomic_store(reinterpret_cast<unsigned*>(p), v,
                     __ATOMIC_RELAXED, __HIP_MEMORY_SCOPE_AGENT);
}
static __device__ __forceinline__ int afadd(int* p, int v) {
  return __hip_atomic_fetch_add(p, v, __ATOMIC_RELAXED, __HIP_MEMORY_SCOPE_AGENT);
}
static __device__ __forceinline__ int afadd_rel(int* p, int v) {
  return __hip_atomic_fetch_add(p, v, __ATOMIC_RELEASE, __HIP_MEMORY_SCOPE_AGENT);
}

static __device__ __forceinline__ int read_xcc() {
  int x;
  asm volatile("s_getreg_b32 %0, hwreg(HW_REG_XCC_ID)" : "=s"(x));
  return x & 15;
}

// raw barrier: LDS-visibility only, NO vmcnt drain (stores stay in flight)
#define BARRIER_LGKM() asm volatile("s_waitcnt lgkmcnt(0)\n\ts_barrier" ::: "memory")

// same-L2 (sc0) and device-coherent (sc0 sc1) 16B poll loads — VOLATILE
// (R3 lesson: non-volatile asm loads get CSE'd -> poll never re-reads)
#define LDQ_S(dst, base, off)                                                   \
  asm volatile("global_load_dwordx4 %0, %1, off offset:" #off " sc0"            \
               : "=v"(dst) : "v"(base))
#define LDQ_D(dst, base, off)                                                   \
  asm volatile("global_load_dwordx4 %0, %1, off offset:" #off " sc0 sc1"        \
               : "=v"(dst) : "v"(base))
#define LD16(M)                                                                 \
  M(af[0],  b0, 0);    M(af[1],  b0, 1024); M(af[2],  b0, 2048); M(af[3],  b0, 3072); \
  M(af[4],  b1, 0);    M(af[5],  b1, 1024); M(af[6],  b1, 2048); M(af[7],  b1, 3072); \
  M(af[8],  b2, 0);    M(af[9],  b2, 1024); M(af[10], b2, 2048); M(af[11], b2, 3072); \
  M(af[12], b3, 0);    M(af[13], b3, 1024); M(af[14], b3, 2048); M(af[15], b3, 3072)

// same-L2 4B store (fast-mode publish/poison)
#define STW_S(addr, val)                                                        \
  asm volatile("global_store_dword %0, %1, off sc0" :: "v"(addr), "v"(val))

// ---------------- Kernel 1: fp32 embedding gather (output 1 + LSTM x) -------
__global__ __launch_bounds__(256) void gather_f32(const int* __restrict__ src,
                                                  const float* __restrict__ emb,
                                                  float* __restrict__ out1) {
  int tid = blockIdx.x * 256 + threadIdx.x;   // 0 .. 2097151 (float4 granules)
  int bt = tid >> 7;                          // b*512 + t
  int k4 = (tid & 127) << 2;
  int s  = src[bt];
  float4 v = *reinterpret_cast<const float4*>(emb + (size_t)s * ND + k4);
  *reinterpret_cast<float4*>(out1 + (size_t)bt * ND + k4) = v;
}

// ---------------- Kernel 2: persistent 2-layer LSTM ----------------
// grid = 512 blocks x 320 threads (all co-resident: 2 x 66KB LDS / CU).
// Roles claimed at runtime by XCD; 128 blocks work, 384 exit.
// waves 0..3 (m = wv&1 batch half, kh = wv>>1 K half): compute; NEVER store.
// wave 4: writer — epilogue for step t-1, all publishes/poisons/out0.
template<bool FULL>
__global__ __launch_bounds__(320, 1) void lstm_persist(
    const float* __restrict__ Wk, const float* __restrict__ Wr,
    const float* __restrict__ bias_g,
    const float* __restrict__ x_f32,          // gathered fp32 emb (out1)
    unsigned char* ws, float* __restrict__ out0) {

  __shared__ __attribute__((aligned(16))) char smem[66048];
  __shared__ int s_role, s_fast0, s_fast1;

  const int tid  = threadIdx.x;
  const int lane = tid & 63;
  const int wv   = tid >> 6;                  // 0..4
  const int m    = wv & 1;                    // batch mtile (16 rows)
  const int kh   = wv >> 1;                   // K half (for compute waves)

  int* cl     = reinterpret_cast<int*>(ws);   // claim region
  int* flags  = cl + 32;                      // [64] L1 progress (SMALL only)
  int* xcdtab = cl + 128;                     // [128] claimed xcd per role

  // ---- phase 0: runtime role claim by physical XCD -------------------------
  if (tid == 0) {
    int xcd  = read_xcc();
    int role = -1;
    if (xcd == 0)      { int v = afadd(cl + 0, 1); if (v < 64) role = v; }
    else if (xcd == 1) { int v = afadd(cl + 1, 1); if (v < 64) role = 64 + v; }
    if (role < 0) {
      // fallback pool: wait; fill shortages after timeout (marks layer mixed)
      unsigned long long t0 = __builtin_amdgcn_s_memrealtime();
      for (;;) {
        if (aload_i(cl + 2) >= 128) break;
        if (__builtin_amdgcn_s_memrealtime() - t0 > 6000ull) {   // ~60 us
          int v = afadd(cl + 0, 1);
          if (v < 64) { role = v; astore_i(cl + 3, 1); }
          else {
            v = afadd(cl + 1, 1);
            if (v < 64) { role = 64 + v; astore_i(cl + 4, 1); }
          }
          break;
        }
        __builtin_amdgcn_s_sleep(8);
      }
    }
    if (role >= 0) {
      astore_i(xcdtab + role, xcd + 1);
      afadd_rel(cl + 2, 1);                   // release: tab/mode visible
    }
    s_role = role;
  }
  __syncthreads();
  const int role = s_role;
  if (role < 0) return;                       // 384 helper blocks exit
  if (tid == 0) {                             // rendezvous: all 128 claimed
    int sp = 0;
    while (aload_acq(cl + 2) < 128) {
      if (++sp > SPIN_LIM) break;             // fail-safe, never hang
      __builtin_amdgcn_s_sleep(8);
    }
  }
  __syncthreads();
  if (wv == 0) {                              // verified fast-mode decision
    int x0 = aload_i(xcdtab + lane), x1 = aload_i(xcdtab + 64 + lane);
    int e0 = __all(x0 == __shfl(x0, 0)) && (aload_i(cl + 3) == 0);
    int e1 = __all(x1 == __shfl(x1, 0)) && (aload_i(cl + 4) == 0);
    if (lane == 0) { s_fast0 = e0; s_fast1 = e1; }
  }
  __syncthreads();
  const bool fast0 = (s_fast0 != 0), fast1 = (s_fast1 != 0);

  const int L     = role >> 6;
  const int slice = role & 63;
  const int u0    = slice * 8;

  const float* WkL = Wk + (size_t)L * 512 * NG;
  const float* WrL = Wr + (size_t)L * 512 * NG;

  // ---- phase 1: stage transposed weight slice into LDS: WT[32 cols][1032 k]
  short* WT = reinterpret_cast<short*>(smem);
  for (int idx = tid; idx < 1024 * 32; idx += 320) {
    int k = idx >> 5, c = idx & 31;
    int gc = (c >> 3) * 512 + u0 + (c & 7);        // cols ordered [i8|f8|g8|o8]
    float v = (k < 512) ? WkL[(size_t)k * NG + gc]
                        : WrL[(size_t)(k - 512) * NG + gc];
    WT[c * 1032 + k] = (short)f2bf(v);
  }
  __syncthreads();

  // ---- preload static B fragments into VGPRs (compute waves only)
  short8 Bf[2][16];
  if (wv < 4) {
    int colr = lane & 15;
    int q    = lane >> 4;
#pragma unroll
    for (int n = 0; n < 2; ++n)
#pragma unroll
      for (int kt2 = 0; kt2 < 16; ++kt2) {
        int k = (kh * 16 + kt2) * 32 + q * 8;
        Bf[n][kt2] = *reinterpret_cast<const short8*>(WT + (n * 16 + colr) * 1032 + k);
      }
  }
  __syncthreads();

  // ---- LDS reused: parity-double-buffered z partials + bias
  float* zb   = reinterpret_cast<float*>(smem);   // 2 x 2112 floats
  float* blds = zb + 2 * 2112;                    // 32 floats
  if (tid < 32) {
    int gc = (tid >> 3) * 512 + u0 + (tid & 7);
    blds[tid] = bias_g[L * NG + gc];
  }
  __syncthreads();

  unsigned char* h1buf = ws + H1_OFF;
  unsigned char* h0f   = ws + H0F_OFF;
  unsigned char* h0m   = ws + H0M_OFF;

  // writer-wave per-lane mapping: 4 hidden units per lane
  const int eb   = lane >> 1;                // batch row 0..31
  const int eu_b = (lane & 1) * 4;           // eu base: 0 or 4
  const size_t pub_base = (size_t)(eb >> 4) * 16384 + (size_t)(u0 >> 5) * 1024 +
                          (size_t)((u0 >> 3) & 3) * 256 + (size_t)(eb & 15) * 16 +
                          (size_t)eu_b * 2;
  float creg0 = 0.f, creg1 = 0.f, creg2 = 0.f, creg3 = 0.f;

  for (int t = 0; t <= NS; ++t) {
    if (wv < 4 && t < NS) {
      short8 af[16];

      if (L == 0 && kh == 0) {
        // ---- x waves: pure loads; bp only in SMALL mode (mirror is 32-deep)
        int bpf = 0;
        const bool bp = (!FULL) && (wv == 0) && ((t & 3) == 0) && (t >= 16);
        if (bp) bpf = aload_i(flags + lane);
        int bb = m * 16 + (lane & 15);
        const float* xr = x_f32 + ((size_t)bb * NS + t) * ND + (lane >> 4) * 8;
#pragma unroll
        for (int kt2 = 0; kt2 < 16; ++kt2) {
          float4 v0 = *reinterpret_cast<const float4*>(xr + kt2 * 32);
          float4 v1 = *reinterpret_cast<const float4*>(xr + kt2 * 32 + 4);
          af[kt2] = pack8(v0, v1);
        }
        if (bp) {
          int sp = 0;
          while (!__all(bpf >= t - 10)) {
            if (++sp > 4096) break;            // capped: no 30ms outlier
            __builtin_amdgcn_s_sleep(4);
            bpf = aload_i(flags + lane);
          }
        }
      } else if (t == 0 && kh == 1) {
        // self-layer h[-1] == 0 (slots start poisoned; never read them)
        const short8 zz = {0, 0, 0, 0, 0, 0, 0, 0};
#pragma unroll
        for (int kt2 = 0; kt2 < 16; ++kt2) af[kt2] = zz;
      } else {
        const unsigned char* hb;
        bool fp;
        if (L == 0) {          // self-recurrence h0[t-1]
          fp = fast0;
          hb = fp ? h0f + (size_t)((t - 1) & 15) * 32768
                  : h0m + (size_t)(FULL ? (t - 1) : ((t - 1) & 31)) * 32768;
        } else if (kh == 0) {  // cross-layer h0[t] — always agent (mirror)
          fp = false;
          hb = h0m + (size_t)(FULL ? t : (t & 31)) * 32768;
        } else {               // self-recurrence h1[t-1]
          fp = fast1;
          hb = h1buf + (size_t)((t - 1) & 15) * 32768;
        }
        const unsigned char* ha = hb + (size_t)m * 16384 +
                                  (size_t)(lane >> 4) * 256 + (size_t)(lane & 15) * 16;
        if (fp) {
          // ---- same-L2 poll: sc0 loads; every 16th round escalates to IC
          // (livelock insurance; in clean fast mode it never binds)
          const unsigned char* b0 = ha;
          const unsigned char* b1 = ha + 4096;
          const unsigned char* b2 = ha + 8192;
          const unsigned char* b3 = ha + 12288;
          int spin = 0;
          for (;;) {
            if ((spin & 15) == 15) { LD16(LDQ_D); } else { LD16(LDQ_S); }
            asm volatile("s_waitcnt vmcnt(0)" ::: "memory");
            __builtin_amdgcn_sched_barrier(0);
            unsigned ok = 1u;
#pragma unroll
            for (int i = 0; i < 16; ++i) {
              u32x4 w = __builtin_bit_cast(u32x4, af[i]);
              ok &= (unsigned)(w[0] != POISON) & (unsigned)(w[1] != POISON) &
                    (unsigned)(w[2] != POISON) & (unsigned)(w[3] != POISON);
            }
            if (ok) break;
            if (++spin > SPIN_LIM) break;      // fail loudly, never hang
            if (spin > 8) __builtin_amdgcn_s_sleep(1);
          }
        } else {
          // ---- agent-scope poll (R4-proven path)
          int spin = 0;
          for (;;) {
#pragma unroll
            for (int i = 0; i < 4; ++i)
#pragma unroll
              for (int j = 0; j < 4; ++j) {
                unsigned long long* ap =
                    reinterpret_cast<unsigned long long*>(&af[i * 4 + j]);
                const unsigned char* p = ha + (size_t)i * 4096 + (size_t)j * 1024;
                ap[0] = aload64(p);
                ap[1] = aload64(p + 8);
              }
            unsigned ok = 1u;
#pragma unroll
            for (int i = 0; i < 16; ++i) {
              u32x4 w = __builtin_bit_cast(u32x4, af[i]);
              ok &= (unsigned)(w[0] != POISON) & (unsigned)(w[1] != POISON) &
                    (unsigned)(w[2] != POISON) & (unsigned)(w[3] != POISON);
            }
            if (ok) break;
            if (++spin > SPIN_LIM) break;
            if (spin > 8) __builtin_amdgcn_s_sleep(1);
          }
        }
      }

      // ---- MFMA: 16 ktiles x 2 ntiles, fp32 accum
      f32x4 acc0 = {0.f, 0.f, 0.f, 0.f}, acc1 = {0.f, 0.f, 0.f, 0.f};
#pragma unroll
      for (int kt2 = 0; kt2 < 16; ++kt2) {
        bf16x8 a = __builtin_bit_cast(bf16x8, af[kt2]);
        acc0 = __builtin_amdgcn_mfma_f32_16x16x32_bf16(
            a, __builtin_bit_cast(bf16x8, Bf[0][kt2]), acc0, 0, 0, 0);
        acc1 = __builtin_amdgcn_mfma_f32_16x16x32_bf16(
            a, __builtin_bit_cast(bf16x8, Bf[1][kt2]), acc1, 0, 0, 0);
      }

      // ---- z partials -> LDS parity buffer
      {
        int r0 = m * 16 + (lane >> 4) * 4;
        int cc = lane & 15;
        float* zp = zb + (t & 1) * 2112 + kh * (32 * 33);
#pragma unroll
        for (int r = 0; r < 4; ++r) {
          zp[(r0 + r) * 33 + cc]      = acc0[r];
          zp[(r0 + r) * 33 + 16 + cc] = acc1[r];
        }
      }
    } else if (wv == 4 && t > 0) {
      // ---- writer wave: finish step tp = t-1 (its z was written last iter)
      const int tp = t - 1;
      const float* zq = zb + (tp & 1) * 2112;
      float hv0, hv1, hv2, hv3;
      {
        float hv[4];
#pragma unroll
        for (int j = 0; j < 4; ++j) {
          int eu = eu_b + j;
          float zi = zq[eb * 33 + eu]      + zq[1056 + eb * 33 + eu]      + blds[eu];
          float zf = zq[eb * 33 + 8 + eu]  + zq[1056 + eb * 33 + 8 + eu]  + blds[8 + eu];
          float zg = zq[eb * 33 + 16 + eu] + zq[1056 + eb * 33 + 16 + eu] + blds[16 + eu];
          float zo = zq[eb * 33 + 24 + eu] + zq[1056 + eb * 33 + 24 + eu] + blds[24 + eu];
          float ig = 1.f / (1.f + __expf(-zi));
          float fg = 1.f / (1.f + __expf(-zf));
          float e2 = __expf(-2.f * zg);
          float gg = (1.f - e2) / (1.f + e2);
          float og = 1.f / (1.f + __expf(-zo));
          float c_old = (j == 0) ? creg0 : (j == 1) ? creg1 : (j == 2) ? creg2 : creg3;
          float c_new = fg * c_old + ig * gg;
          if (j == 0) creg0 = c_new; else if (j == 1) creg1 = c_new;
          else if (j == 2) creg2 = c_new; else creg3 = c_new;
          float ec = __expf(-2.f * c_new);
          hv[j] = og * ((1.f - ec) / (1.f + ec));
        }
        hv0 = hv[0]; hv1 = hv[1]; hv2 = hv[2]; hv3 = hv[3];
      }

      unsigned p0 = ((unsigned)f2bf(hv0) & 0xffffu) | ((unsigned)f2bf(hv1) << 16);
      unsigned p1 = ((unsigned)f2bf(hv2) & 0xffffu) | ((unsigned)f2bf(hv3) << 16);

      if (L == 0) {
        // mirror publish (always; agent scope for cross-XCD L1 readers)
        unsigned char* dm = h0m + (size_t)(FULL ? tp : (tp & 31)) * 32768 + pub_base;
        astore_u(dm, p0); astore_u(dm + 4, p1);
        if (!FULL) {  // 32-deep mirror: recycle poison (readers bounded by bp)
          unsigned char* pm = h0m + (size_t)((tp + 16) & 31) * 32768 + pub_base;
          astore_u(pm, POISON); astore_u(pm + 4, POISON);
        }
        if (fast0) {  // same-L2 fast publish + poison recycle (16-deep)
          unsigned char* df = h0f + (size_t)(tp & 15) * 32768 + pub_base;
          unsigned char* pf = h0f + (size_t)((tp + 8) & 15) * 32768 + pub_base;
          STW_S(df, p0); STW_S(df + 4, p1);
          STW_S(pf, POISON); STW_S(pf + 4, POISON);
        }
      } else {
        unsigned char* dst = h1buf + (size_t)(tp & 15) * 32768 + pub_base;
        unsigned char* pb  = h1buf + (size_t)((tp + 8) & 15) * 32768 + pub_base;
        if (fast1) {  // producers+consumers share one L2
          STW_S(dst, p0); STW_S(dst + 4, p1);
          STW_S(pb, POISON); STW_S(pb + 4, POISON);
        } else {
          astore_u(dst, p0); astore_u(dst + 4, p1);
          astore_u(pb, POISON); astore_u(pb + 4, POISON);
        }
        float4 o4 = make_float4(hv0, hv1, hv2, hv3);
        *reinterpret_cast<float4*>(
            out0 + ((size_t)eb * NS + tp) * ND + u0 + eu_b) = o4;
        if (!FULL && lane == 0) astore_i(flags + slice, tp);  // bp progress
      }
      // cap outstanding stores; never a full drain
      asm volatile("s_waitcnt vmcnt(8)" ::: "memory");
    }

    BARRIER_LGKM();   // one barrier/iter: z[t] visible to wave4 at iter t+1
  }
}

extern "C" void kernel_launch(void* const* d_in, const int* in_sizes, int n_in,
                              void* d_out, int out_size, void* d_ws, size_t ws_size,
                              hipStream_t stream) {
  const int*   src = (const int*)d_in[0];
  // d_in[1] = source_len (unused by the reference computation)
  const float* emb = (const float*)d_in[2];
  const float* Wk  = (const float*)d_in[3];
  const float* Wr  = (const float*)d_in[4];
  const float* bg  = (const float*)d_in[5];

  float* out0 = (float*)d_out;                        // LSTM output [32,512,512]
  float* out1 = out0 + (size_t)NB * NS * ND;          // source_emb [32,512,512]
  unsigned char* ws = (unsigned char*)d_ws;

  // output 1: embedding gather (also the fp32 x source for layer 0)
  gather_f32<<<8192, 256, 0, stream>>>(src, emb, out1);

  bool full = ws_size >= WS_FULL;
  size_t poison_bytes = (full ? WS_FULL : WS_SMALL) - H1_OFF;

  // per-call init: claim/flags -> 0, all h slots -> poison (0xFF)
  hipMemsetAsync(ws, 0, CLAIM_BYTES, stream);
  hipMemsetAsync(ws + H1_OFF, 0xFF, poison_bytes, stream);

  if (full) lstm_persist<true ><<<512, 320, 0, stream>>>(Wk, Wr, bg, out1, ws, out0);
  else      lstm_persist<false><<<512, 320, 0, stream>>>(Wk, Wr, bg, out1, ws, out0);
}

// Round 6
// 3599.372 us; speedup vs baseline: 1.0338x; 1.0338x over previous
//
#include <hip/hip_runtime.h>
#include <hip/hip_bf16.h>
#include <cstddef>
#include <cstdint>

// Problem constants
#define NB 32          // batch
#define NS 512         // seq len
#define ND 512         // d_model == hid
#define NG 2048        // 4*hid gate cols per layer

// ws layout (R6 = R4 minus writer-wave serialization, minus all flags):
//   h0 : 512 slots x 32768 B, slot = t, WRITE-ONCE (no recycle, no bp)
//   h1 : 4 slots x 32768 B, slot = t & 3, poison-recycled
// Total 16,908,288 B == the R0/R2-proven ws footprint.
// One 32KB slot, element (b,k):
//   (b>>4)*16384 + (k>>5)*1024 + ((k>>3)&3)*256 + (b&15)*16 + (k&7)*2
// (a polling wave reads a contiguous 16KB half).
// Protocol (all R4-proven): publishes/polls are relaxed agent-scope atomics;
// legit |h|<1 never encodes bf16 0xFFFF -> word 0xFFFFFFFF impossible;
// publish and check granularity both 4B -> no torn reads. NO store-drain
// anywhere: raw lgkmcnt barriers only; store acks retire inside the NEXT
// step's poll vmcnt(0), in parallel with the poll loads (max, not sum).
// h1 slot-recycle safety (R1/R2-proven): the poison of slot (t+2)&3 (holding
// h1[t-2]) is control-dependent on this block's poll of h1[t-1]; any peer's
// reads of h1[t-2] retired before that peer published h1[t-1]. Skew < 2 steps
// because the full-vector poll is a per-step rendezvous.
#define H0_OFF   0
#define H1_OFF   (512 * 32768)
#define WS_NEED  (H1_OFF + 4 * 32768)        // 16,908,288 (proven fits)

#define POISON   0xFFFFFFFFu
#define SPIN_LIM (1 << 17)

typedef __attribute__((ext_vector_type(8))) short short8;
typedef __attribute__((ext_vector_type(8))) __bf16 bf16x8;
typedef __attribute__((ext_vector_type(4))) float f32x4;
typedef __attribute__((ext_vector_type(4))) unsigned int u32x4;

static __device__ __forceinline__ unsigned short f2bf(float f) {
  __hip_bfloat16 h = __float2bfloat16(f);
  return __builtin_bit_cast(unsigned short, h);
}

static __device__ __forceinline__ short8 pack8(float4 a, float4 b) {
  short8 r;
  r[0] = (short)f2bf(a.x); r[1] = (short)f2bf(a.y);
  r[2] = (short)f2bf(a.z); r[3] = (short)f2bf(a.w);
  r[4] = (short)f2bf(b.x); r[5] = (short)f2bf(b.y);
  r[6] = (short)f2bf(b.z); r[7] = (short)f2bf(b.w);
  return r;
}

static __device__ __forceinline__ unsigned long long aload64(const unsigned char* p) {
  return __hip_atomic_load(reinterpret_cast<const unsigned long long*>(p),
                           __ATOMIC_RELAXED, __HIP_MEMORY_SCOPE_AGENT);
}
static __device__ __forceinline__ void astore_u(unsigned char* p, unsigned v) {
  __hip_atomic_store(reinterpret_cast<unsigned*>(p), v,
                     __ATOMIC_RELAXED, __HIP_MEMORY_SCOPE_AGENT);
}

// raw barrier: LDS-visibility only, NO vmcnt drain (stores stay in flight)
#define BARRIER_LGKM() asm volatile("s_waitcnt lgkmcnt(0)\n\ts_barrier" ::: "memory")

// ---------------- Kernel 1: fp32 embedding gather (output 1 + LSTM x) -------
__global__ __launch_bounds__(256) void gather_f32(const int* __restrict__ src,
                                                  const float* __restrict__ emb,
                                                  float* __restrict__ out1) {
  int tid = blockIdx.x * 256 + threadIdx.x;   // 0 .. 2097151 (float4 granules)
  int bt = tid >> 7;                          // b*512 + t
  int k4 = (tid & 127) << 2;
  int s  = src[bt];
  float4 v = *reinterpret_cast<const float4*>(emb + (size_t)s * ND + k4);
  *reinterpret_cast<float4*>(out1 + (size_t)bt * ND + k4) = v;
}

// ---------------- Kernel 2: persistent 2-layer LSTM ----------------
// grid = 128 blocks x 256 threads (4 waves), 1 block/CU.
// L = bid>>6, slice = bid&63 (8 hidden units / 32 gate cols per block).
// waves 0..3: m = wv&1 (batch half), kh = wv>>1 (K half). ALL waves compute
// the distributed epilogue (1 hidden unit per thread) and publish directly;
// no dedicated writer wave, no store-drain anywhere in the loop.
__global__ __launch_bounds__(256, 1) void lstm_persist(
    const float* __restrict__ Wk, const float* __restrict__ Wr,
    const float* __restrict__ bias_g,
    const float* __restrict__ x_f32,          // gathered fp32 emb (out1)
    unsigned char* ws, float* __restrict__ out0) {

  __shared__ __attribute__((aligned(16))) char smem[66048];

  const int tid   = threadIdx.x;
  const int bid   = blockIdx.x;
  const int L     = bid >> 6;
  const int slice = bid & 63;
  const int u0    = slice * 8;
  const int lane  = tid & 63;
  const int wv    = tid >> 6;                 // 0..3
  const int m     = wv & 1;                   // batch mtile (16 rows)
  const int kh    = wv >> 1;                  // K half

  const float* WkL = Wk + (size_t)L * 512 * NG;
  const float* WrL = Wr + (size_t)L * 512 * NG;

  // ---- phase 1: stage transposed weight slice into LDS: WT[32 cols][1032 k]
  short* WT = reinterpret_cast<short*>(smem);
  for (int idx = tid; idx < 1024 * 32; idx += 256) {
    int k = idx >> 5, c = idx & 31;
    int gc = (c >> 3) * 512 + u0 + (c & 7);        // cols ordered [i8|f8|g8|o8]
    float v = (k < 512) ? WkL[(size_t)k * NG + gc]
                        : WrL[(size_t)(k - 512) * NG + gc];
    WT[c * 1032 + k] = (short)f2bf(v);
  }
  __syncthreads();

  // ---- preload static B fragments into VGPRs (32 frags = 128 VGPRs/thread)
  short8 Bf[2][16];
  {
    int colr = lane & 15;
    int q    = lane >> 4;
#pragma unroll
    for (int n = 0; n < 2; ++n)
#pragma unroll
      for (int kt2 = 0; kt2 < 16; ++kt2) {
        int k = (kh * 16 + kt2) * 32 + q * 8;
        Bf[n][kt2] = *reinterpret_cast<const short8*>(WT + (n * 16 + colr) * 1032 + k);
      }
  }
  __syncthreads();

  // ---- LDS reused: parity-double-buffered z partials + bias
  float* zb   = reinterpret_cast<float*>(smem);   // 2 x 2112 floats
  float* blds = zb + 2 * 2112;                    // 32 floats
  if (tid < 32) {
    int gc = (tid >> 3) * 512 + u0 + (tid & 7);
    blds[tid] = bias_g[L * NG + gc];
  }
  __syncthreads();

  unsigned char* h0buf = ws + H0_OFF;
  unsigned char* h1buf = ws + H1_OFF;

  // distributed epilogue mapping: thread (eb, eu) owns one hidden unit
  const int eb = tid >> 3, eu = tid & 7;
  const size_t pub_off = (size_t)(eb >> 4) * 16384 + (size_t)(u0 >> 5) * 1024 +
                         (size_t)((u0 >> 3) & 3) * 256 + (size_t)(eb & 15) * 16 +
                         (size_t)eu * 2;
  float creg = 0.f;

  for (int t = 0; t < NS; ++t) {
    short8 af[16];

    if (L == 0 && kh == 0) {
      // ---- x waves: pure loads, no dependency (overlaps peers' polls)
      int bb = m * 16 + (lane & 15);
      const float* xr = x_f32 + ((size_t)bb * NS + t) * ND + (lane >> 4) * 8;
#pragma unroll
      for (int kt2 = 0; kt2 < 16; ++kt2) {
        float4 v0 = *reinterpret_cast<const float4*>(xr + kt2 * 32);
        float4 v1 = *reinterpret_cast<const float4*>(xr + kt2 * 32 + 4);
        af[kt2] = pack8(v0, v1);
      }
    } else if (t == 0 && kh == 1) {
      // self-layer h[-1] == 0 (slots start poisoned; never read them)
      const short8 zz = {0, 0, 0, 0, 0, 0, 0, 0};
#pragma unroll
      for (int kt2 = 0; kt2 < 16; ++kt2) af[kt2] = zz;
    } else {
      // ---- data poll: relaxed agent atomic loads (R4-proven coherent).
      // The successful round's loads ARE the MFMA A-fragments. The first
      // round's vmcnt(0) also retires last step's publish stores -- in
      // parallel with the loads, never serialized ahead of them.
      const unsigned char* hb;
      if (L == 0)       hb = h0buf + (size_t)(t - 1) * 32768;        // h0[t-1]
      else if (kh == 0) hb = h0buf + (size_t)t * 32768;              // h0[t]
      else              hb = h1buf + (size_t)((t - 1) & 3) * 32768;  // h1[t-1]
      const unsigned char* ha = hb + (size_t)m * 16384 +
                                (size_t)(lane >> 4) * 256 + (size_t)(lane & 15) * 16;
      int spin = 0;
      for (;;) {
#pragma unroll
        for (int i = 0; i < 4; ++i)
#pragma unroll
          for (int j = 0; j < 4; ++j) {
            unsigned long long* ap =
                reinterpret_cast<unsigned long long*>(&af[i * 4 + j]);
            const unsigned char* p = ha + (size_t)i * 4096 + (size_t)j * 1024;
            ap[0] = aload64(p);
            ap[1] = aload64(p + 8);
          }
        unsigned ok = 1u;
#pragma unroll
        for (int i = 0; i < 16; ++i) {
          u32x4 w = __builtin_bit_cast(u32x4, af[i]);
          ok &= (unsigned)(w[0] != POISON) & (unsigned)(w[1] != POISON) &
                (unsigned)(w[2] != POISON) & (unsigned)(w[3] != POISON);
        }
        if (ok) break;
        if (++spin > SPIN_LIM) break;          // fail-safe: fail loudly
        if (spin > 8) __builtin_amdgcn_s_sleep(1);
      }
    }

    // ---- MFMA: 16 ktiles x 2 ntiles, fp32 accum
    f32x4 acc0 = {0.f, 0.f, 0.f, 0.f}, acc1 = {0.f, 0.f, 0.f, 0.f};
#pragma unroll
    for (int kt2 = 0; kt2 < 16; ++kt2) {
      bf16x8 a = __builtin_bit_cast(bf16x8, af[kt2]);
      acc0 = __builtin_amdgcn_mfma_f32_16x16x32_bf16(
          a, __builtin_bit_cast(bf16x8, Bf[0][kt2]), acc0, 0, 0, 0);
      acc1 = __builtin_amdgcn_mfma_f32_16x16x32_bf16(
          a, __builtin_bit_cast(bf16x8, Bf[1][kt2]), acc1, 0, 0, 0);
    }

    // ---- z partials -> LDS parity buffer (col=lane&15, row=(lane>>4)*4+r)
    {
      int r0 = m * 16 + (lane >> 4) * 4;
      int cc = lane & 15;
      float* zp = zb + (t & 1) * 2112 + kh * (32 * 33);
#pragma unroll
      for (int r = 0; r < 4; ++r) {
        zp[(r0 + r) * 33 + cc]      = acc0[r];
        zp[(r0 + r) * 33 + 16 + cc] = acc1[r];
      }
    }
    BARRIER_LGKM();   // the ONLY barrier per step (LDS visibility, no drain)

    // ---- distributed epilogue: one hidden unit per thread
    {
      const float* zq = zb + (t & 1) * 2112;
      float zi = zq[eb * 33 + eu]      + zq[1056 + eb * 33 + eu]      + blds[eu];
      float zf = zq[eb * 33 + 8 + eu]  + zq[1056 + eb * 33 + 8 + eu]  + blds[8 + eu];
      float zg = zq[eb * 33 + 16 + eu] + zq[1056 + eb * 33 + 16 + eu] + blds[16 + eu];
      float zo = zq[eb * 33 + 24 + eu] + zq[1056 + eb * 33 + 24 + eu] + blds[24 + eu];
      float ig = 1.f / (1.f + __expf(-zi));
      float fg = 1.f / (1.f + __expf(-zf));
      float e2 = __expf(-2.f * zg);
      float gg = (1.f - e2) / (1.f + e2);
      float og = 1.f / (1.f + __expf(-zo));
      creg = fg * creg + ig * gg;
      float ec = __expf(-2.f * creg);
      float th = (1.f - ec) / (1.f + ec);
      float hv = og * th;

      unsigned hu  = f2bf(hv);
      unsigned hi  = (unsigned)__shfl_down((int)hu, 1);
      float    hvn = __shfl_down(hv, 1);

      // fire-and-forget publishes: no drain follows; acks retire inside the
      // next step's poll vmcnt(0), in parallel with its loads.
      if ((eu & 1) == 0) {
        unsigned packed = (hu & 0xffffu) | (hi << 16);
        if (L == 0) {
          astore_u(h0buf + (size_t)t * 32768 + pub_off, packed);   // write-once
        } else {
          astore_u(h1buf + (size_t)(t & 3) * 32768 + pub_off, packed);
          // recycle poison: slot (t+2)&3 holds h1[t-2]; all readers retired
          astore_u(h1buf + (size_t)((t + 2) & 3) * 32768 + pub_off, POISON);
          // final output: 2 consecutive units -> one float2 store
          *reinterpret_cast<float2*>(out0 + ((size_t)eb * NS + t) * ND + u0 + eu) =
              make_float2(hv, hvn);
        }
      }
    }
    // no second barrier: next iteration's z writes go to the other parity
  }
}

extern "C" void kernel_launch(void* const* d_in, const int* in_sizes, int n_in,
                              void* d_out, int out_size, void* d_ws, size_t ws_size,
                              hipStream_t stream) {
  const int*   src = (const int*)d_in[0];
  // d_in[1] = source_len (unused by the reference computation)
  const float* emb = (const float*)d_in[2];
  const float* Wk  = (const float*)d_in[3];
  const float* Wr  = (const float*)d_in[4];
  const float* bg  = (const float*)d_in[5];

  float* out0 = (float*)d_out;                        // LSTM output [32,512,512]
  float* out1 = out0 + (size_t)NB * NS * ND;          // source_emb [32,512,512]
  unsigned char* ws = (unsigned char*)d_ws;

  // output 1: embedding gather (also the fp32 x source for layer 0)
  gather_f32<<<8192, 256, 0, stream>>>(src, emb, out1);

  // one-shot poison of ALL h slots (h0 write-once full-depth + h1 4-deep)
  hipMemsetAsync(ws, 0xFF, WS_NEED, stream);

  lstm_persist<<<128, 256, 0, stream>>>(Wk, Wr, bg, out1, ws, out0);
}

// Round 7
// 3417.978 us; speedup vs baseline: 1.0887x; 1.0531x over previous
//
#include <hip/hip_runtime.h>
#include <hip/hip_bf16.h>
#include <cstddef>
#include <cstdint>

// Problem constants
#define NB 32          // batch
#define NS 512         // seq len
#define ND 512         // d_model == hid
#define NG 2048        // 4*hid gate cols per layer

// ws layout (R7 = R4 + 4-wide writer stage + zero flags):
//   h0 : 512 slots x 32768 B, slot = t, WRITE-ONCE (no recycle, no flags)
//   h1 : 8 slots x 32768 B, slot = t & 7, writer-poison-recycled
// Total 17,039,360 B (R5 proved ws_size >= 17.8 MB on this harness).
// One 32KB slot, element (b,k):
//   (b>>4)*16384 + (k>>5)*1024 + ((k>>3)&3)*256 + (b&15)*16 + (k&7)*2
// (a polling wave reads a contiguous 16KB batch-half).
// Protocol (R4-proven): publishes/polls are relaxed agent-scope atomics;
// legit |h|<1 never encodes bf16 0xFFFF -> word 0xFFFFFFFF impossible;
// publish and check granularity both 4B -> no torn reads.
// Invariant (proven R4 vs R0/R2/R6): COMPUTE WAVES NEVER STORE -> their poll
// vmcnt(0) never drains store acks. All global stores come from the 4 writer
// waves, capped by vmcnt(8), never drained. Barriers are raw lgkm-only.
// h1 recycle safety: when publishing h1[p], writers poison slot (p+4)&7
// (holds h1[p-4]). Peers' reads of h1[p-4] happened at their iter p-3 and
// retired before they published h1[p-1]; this block observed h1[p-1] complete
// (its compute waves' poll at iter p) BEFORE the barrier that precedes the
// writer's poison at iter p+1 -> poison is temporally after all reads. Margin
// 3 steps vs intra-layer skew <= ~1 (full-vector poll is a rendezvous).
#define H0_OFF   0
#define H1_OFF   (512 * 32768)
#define WS_NEED  ((size_t)H1_OFF + 8ull * 32768ull)   // 17,039,360

#define POISON   0xFFFFFFFFu
#define SPIN_LIM (1 << 17)

typedef __attribute__((ext_vector_type(8))) short short8;
typedef __attribute__((ext_vector_type(8))) __bf16 bf16x8;
typedef __attribute__((ext_vector_type(4))) float f32x4;
typedef __attribute__((ext_vector_type(4))) unsigned int u32x4;

static __device__ __forceinline__ unsigned short f2bf(float f) {
  __hip_bfloat16 h = __float2bfloat16(f);
  return __builtin_bit_cast(unsigned short, h);
}

static __device__ __forceinline__ short8 pack8(float4 a, float4 b) {
  short8 r;
  r[0] = (short)f2bf(a.x); r[1] = (short)f2bf(a.y);
  r[2] = (short)f2bf(a.z); r[3] = (short)f2bf(a.w);
  r[4] = (short)f2bf(b.x); r[5] = (short)f2bf(b.y);
  r[6] = (short)f2bf(b.z); r[7] = (short)f2bf(b.w);
  return r;
}

static __device__ __forceinline__ unsigned long long aload64(const unsigned char* p) {
  return __hip_atomic_load(reinterpret_cast<const unsigned long long*>(p),
                           __ATOMIC_RELAXED, __HIP_MEMORY_SCOPE_AGENT);
}
static __device__ __forceinline__ void astore_u(unsigned char* p, unsigned v) {
  __hip_atomic_store(reinterpret_cast<unsigned*>(p), v,
                     __ATOMIC_RELAXED, __HIP_MEMORY_SCOPE_AGENT);
}

// raw barrier: LDS-visibility only, NO vmcnt drain (stores stay in flight)
#define BARRIER_LGKM() asm volatile("s_waitcnt lgkmcnt(0)\n\ts_barrier" ::: "memory")

// ---------------- Kernel 1: fp32 embedding gather (output 1 + LSTM x) -------
__global__ __launch_bounds__(256) void gather_f32(const int* __restrict__ src,
                                                  const float* __restrict__ emb,
                                                  float* __restrict__ out1) {
  int tid = blockIdx.x * 256 + threadIdx.x;   // 0 .. 2097151 (float4 granules)
  int bt = tid >> 7;                          // b*512 + t
  int k4 = (tid & 127) << 2;
  int s  = src[bt];
  float4 v = *reinterpret_cast<const float4*>(emb + (size_t)s * ND + k4);
  *reinterpret_cast<float4*>(out1 + (size_t)bt * ND + k4) = v;
}

// ---------------- Kernel 2: persistent 2-layer LSTM ----------------
// grid = 128 blocks x 512 threads (8 waves), 1 block/CU.
// L = bid>>6, slice = bid&63 (8 hidden units / 32 gate cols per block).
// waves 0..3 (m = wv&1 batch half, kh = wv>>1 K half): compute; NEVER store.
// waves 4..7: writer stage — epilogue for step t-1 at 1 unit/thread, all
// publishes / poisons / out0 issued from these 4 waves in parallel.
__global__ __launch_bounds__(512, 1) void lstm_persist(
    const float* __restrict__ Wk, const float* __restrict__ Wr,
    const float* __restrict__ bias_g,
    const float* __restrict__ x_f32,          // gathered fp32 emb (out1)
    unsigned char* ws, float* __restrict__ out0) {

  __shared__ __attribute__((aligned(16))) char smem[66048];

  const int tid   = threadIdx.x;
  const int bid   = blockIdx.x;
  const int L     = bid >> 6;
  const int slice = bid & 63;
  const int u0    = slice * 8;
  const int lane  = tid & 63;
  const int wv    = tid >> 6;                 // 0..7
  const int m     = wv & 1;                   // batch mtile (compute waves)
  const int kh    = wv >> 1;                  // K half (compute waves)

  const float* WkL = Wk + (size_t)L * 512 * NG;
  const float* WrL = Wr + (size_t)L * 512 * NG;

  // ---- phase 1: stage transposed weight slice into LDS: WT[32 cols][1032 k]
  short* WT = reinterpret_cast<short*>(smem);
  for (int idx = tid; idx < 1024 * 32; idx += 512) {
    int k = idx >> 5, c = idx & 31;
    int gc = (c >> 3) * 512 + u0 + (c & 7);        // cols ordered [i8|f8|g8|o8]
    float v = (k < 512) ? WkL[(size_t)k * NG + gc]
                        : WrL[(size_t)(k - 512) * NG + gc];
    WT[c * 1032 + k] = (short)f2bf(v);
  }
  __syncthreads();

  // ---- preload static B fragments into VGPRs (compute waves only)
  short8 Bf[2][16];
  if (wv < 4) {
    int colr = lane & 15;
    int q    = lane >> 4;
#pragma unroll
    for (int n = 0; n < 2; ++n)
#pragma unroll
      for (int kt2 = 0; kt2 < 16; ++kt2) {
        int k = (kh * 16 + kt2) * 32 + q * 8;
        Bf[n][kt2] = *reinterpret_cast<const short8*>(WT + (n * 16 + colr) * 1032 + k);
      }
  }
  __syncthreads();

  // ---- LDS reused: parity-double-buffered z partials + bias
  float* zb   = reinterpret_cast<float*>(smem);   // 2 x 2112 floats
  float* blds = zb + 2 * 2112;                    // 32 floats
  if (tid < 32) {
    int gc = (tid >> 3) * 512 + u0 + (tid & 7);
    blds[tid] = bias_g[L * NG + gc];
  }
  __syncthreads();

  unsigned char* h0buf = ws + H0_OFF;
  unsigned char* h1buf = ws + H1_OFF;

  // writer-stage mapping: waves 4..7, 1 hidden unit per thread
  const int widx = (wv - 4) * 64 + lane;     // 0..255 (valid when wv>=4)
  const int eb   = widx >> 3;                // batch row 0..31
  const int eu   = widx & 7;                 // unit within slice 0..7
  const size_t pub_off = (size_t)(eb >> 4) * 16384 + (size_t)(u0 >> 5) * 1024 +
                         (size_t)((u0 >> 3) & 3) * 256 + (size_t)(eb & 15) * 16 +
                         (size_t)eu * 2;
  // bias in registers (writer threads): saves 4 LDS reads / step
  float b_i = blds[eu], b_f = blds[8 + eu], b_g = blds[16 + eu], b_o = blds[24 + eu];
  float creg = 0.f;

  for (int t = 0; t <= NS; ++t) {
    if (wv < 4 && t < NS) {
      short8 af[16];

      if (L == 0 && kh == 0) {
        // ---- x waves: pure loads, no dependency (overlaps peers' polls)
        int bb = m * 16 + (lane & 15);
        const float* xr = x_f32 + ((size_t)bb * NS + t) * ND + (lane >> 4) * 8;
#pragma unroll
        for (int kt2 = 0; kt2 < 16; ++kt2) {
          float4 v0 = *reinterpret_cast<const float4*>(xr + kt2 * 32);
          float4 v1 = *reinterpret_cast<const float4*>(xr + kt2 * 32 + 4);
          af[kt2] = pack8(v0, v1);
        }
      } else if (t == 0 && kh == 1) {
        // self-layer h[-1] == 0 (slots start poisoned; never read them)
        const short8 zz = {0, 0, 0, 0, 0, 0, 0, 0};
#pragma unroll
        for (int kt2 = 0; kt2 < 16; ++kt2) af[kt2] = zz;
      } else {
        // ---- data poll: relaxed agent atomic loads (R4-proven coherent).
        // The successful round's loads ARE the MFMA A-fragments. Pollers
        // have no outstanding stores -> vmcnt waits cover pure loads only.
        const unsigned char* hb;
        if (L == 0)       hb = h0buf + (size_t)(t - 1) * 32768;        // h0[t-1]
        else if (kh == 0) hb = h0buf + (size_t)t * 32768;              // h0[t]
        else              hb = h1buf + (size_t)((t - 1) & 7) * 32768;  // h1[t-1]
        const unsigned char* ha = hb + (size_t)m * 16384 +
                                  (size_t)(lane >> 4) * 256 + (size_t)(lane & 15) * 16;
        int spin = 0;
        for (;;) {
#pragma unroll
          for (int i = 0; i < 4; ++i)
#pragma unroll
            for (int j = 0; j < 4; ++j) {
              unsigned long long* ap =
                  reinterpret_cast<unsigned long long*>(&af[i * 4 + j]);
              const unsigned char* p = ha + (size_t)i * 4096 + (size_t)j * 1024;
              ap[0] = aload64(p);
              ap[1] = aload64(p + 8);
            }
          unsigned ok = 1u;
#pragma unroll
          for (int i = 0; i < 16; ++i) {
            u32x4 w = __builtin_bit_cast(u32x4, af[i]);
            ok &= (unsigned)(w[0] != POISON) & (unsigned)(w[1] != POISON) &
                  (unsigned)(w[2] != POISON) & (unsigned)(w[3] != POISON);
          }
          if (ok) break;
          if (++spin > SPIN_LIM) break;          // fail-safe: fail loudly
          if (spin > 8) __builtin_amdgcn_s_sleep(1);
        }
      }

      // ---- MFMA: 16 ktiles x 2 ntiles, fp32 accum
      f32x4 acc0 = {0.f, 0.f, 0.f, 0.f}, acc1 = {0.f, 0.f, 0.f, 0.f};
#pragma unroll
      for (int kt2 = 0; kt2 < 16; ++kt2) {
        bf16x8 a = __builtin_bit_cast(bf16x8, af[kt2]);
        acc0 = __builtin_amdgcn_mfma_f32_16x16x32_bf16(
            a, __builtin_bit_cast(bf16x8, Bf[0][kt2]), acc0, 0, 0, 0);
        acc1 = __builtin_amdgcn_mfma_f32_16x16x32_bf16(
            a, __builtin_bit_cast(bf16x8, Bf[1][kt2]), acc1, 0, 0, 0);
      }

      // ---- z partials -> LDS parity buffer (col=lane&15, row=(lane>>4)*4+r)
      {
        int r0 = m * 16 + (lane >> 4) * 4;
        int cc = lane & 15;
        float* zp = zb + (t & 1) * 2112 + kh * (32 * 33);
#pragma unroll
        for (int r = 0; r < 4; ++r) {
          zp[(r0 + r) * 33 + cc]      = acc0[r];
          zp[(r0 + r) * 33 + 16 + cc] = acc1[r];
        }
      }
    } else if (wv >= 4 && t > 0) {
      // ---- writer stage: finish step tp = t-1 (its z was written last iter)
      const int tp = t - 1;
      const float* zq = zb + (tp & 1) * 2112;
      float zi = zq[eb * 33 + eu]      + zq[1056 + eb * 33 + eu]      + b_i;
      float zf = zq[eb * 33 + 8 + eu]  + zq[1056 + eb * 33 + 8 + eu]  + b_f;
      float zg = zq[eb * 33 + 16 + eu] + zq[1056 + eb * 33 + 16 + eu] + b_g;
      float zo = zq[eb * 33 + 24 + eu] + zq[1056 + eb * 33 + 24 + eu] + b_o;
      float ig = 1.f / (1.f + __expf(-zi));
      float fg = 1.f / (1.f + __expf(-zf));
      float e2 = __expf(-2.f * zg);
      float gg = (1.f - e2) / (1.f + e2);
      float og = 1.f / (1.f + __expf(-zo));
      creg = fg * creg + ig * gg;
      float ec = __expf(-2.f * creg);
      float th = (1.f - ec) / (1.f + ec);
      float hv = og * th;

      unsigned hu  = f2bf(hv);
      unsigned hi  = (unsigned)__shfl_down((int)hu, 1);
      float    hvn = __shfl_down(hv, 1);

      // fire-and-forget publishes; acks capped by vmcnt(8), never drained
      if ((eu & 1) == 0) {
        unsigned packed = (hu & 0xffffu) | (hi << 16);
        if (L == 0) {
          astore_u(h0buf + (size_t)tp * 32768 + pub_off, packed);   // write-once
        } else {
          astore_u(h1buf + (size_t)(tp & 7) * 32768 + pub_off, packed);
          // recycle poison: slot (tp+4)&7 holds h1[tp-4]; readers retired
          astore_u(h1buf + (size_t)((tp + 4) & 7) * 32768 + pub_off, POISON);
          // final output: 2 consecutive units -> one float2 store
          *reinterpret_cast<float2*>(out0 + ((size_t)eb * NS + tp) * ND + u0 + eu) =
              make_float2(hv, hvn);
        }
      }
      asm volatile("s_waitcnt vmcnt(8)" ::: "memory");   // cap, never drain
    }

    BARRIER_LGKM();   // one barrier/iter: z[t] visible to writers at iter t+1
  }
}

extern "C" void kernel_launch(void* const* d_in, const int* in_sizes, int n_in,
                              void* d_out, int out_size, void* d_ws, size_t ws_size,
                              hipStream_t stream) {
  const int*   src = (const int*)d_in[0];
  // d_in[1] = source_len (unused by the reference computation)
  const float* emb = (const float*)d_in[2];
  const float* Wk  = (const float*)d_in[3];
  const float* Wr  = (const float*)d_in[4];
  const float* bg  = (const float*)d_in[5];

  float* out0 = (float*)d_out;                        // LSTM output [32,512,512]
  float* out1 = out0 + (size_t)NB * NS * ND;          // source_emb [32,512,512]
  unsigned char* ws = (unsigned char*)d_ws;

  // output 1: embedding gather (also the fp32 x source for layer 0)
  gather_f32<<<8192, 256, 0, stream>>>(src, emb, out1);

  // one-shot poison of ALL h slots (h0 write-once full-depth + h1 8-deep)
  hipMemsetAsync(ws, 0xFF, WS_NEED, stream);

  lstm_persist<<<128, 512, 0, stream>>>(Wk, Wr, bg, out1, ws, out0);
}